// Round 9
// baseline (148.254 us; speedup 1.0000x reference)
//
#include <hip/hip_runtime.h>

#define B_ROWS 2048
#define S_LEN  8192
#define PER_LANE 16
#define CHUNK (64 * PER_LANE)      // 1024 elements per chunk
#define CPW 2                      // adjacent chunks per wave (exact in-reg carry)
#define WPB 4                      // waves per block -> block covers one row
#define TPB 256
#define NBLOCKS B_ROWS             // one row per block
#define NPART (NBLOCKS * WPB)      // 8192 per-wave partials
#define HALO 256                   // carry horizon: (1-a)^256 <= 2e-12 for all alphas

// ---- compile-time decay constants ----
constexpr double cpowi(double b, int e) { double r = 1.0; for (int i = 0; i < e; ++i) r *= b; return r; }
constexpr float tof(double x) { return (x < 1.2e-38 && x > -1.2e-38) ? 0.0f : (float)x; }

// Delta-space EMA: du_j = W*du_{j-1} + dx_j  (W = 1-alpha); pd = alpha*du.
#define W0f 0.9f
#define W1f 0.7f
#define W2f 0.4f
#define SE0 0.2f               // 2*alpha (we accumulate 2*h; 0.5 folded into final weights)
#define SE1 0.6f
#define SE2 1.2f
constexpr float NA0 = -(0.1f * 0.1f);   // -alpha^2
constexpr float NA1 = -(0.3f * 0.3f);
constexpr float NA2 = -(0.6f * 0.6f);

// main Kogge-Stone (lane spacing 16); sub-noise steps pruned (validated r2-r7, absmax 0.0)
constexpr float D0_1 = tof(cpowi(0.9, 16)),  D0_2 = tof(cpowi(0.9, 32));
constexpr float D0_4 = tof(cpowi(0.9, 64)),  D0_8 = tof(cpowi(0.9, 128));
constexpr float D1_1 = tof(cpowi(0.7, 16)),  D1_2 = tof(cpowi(0.7, 32));
constexpr float D2_1 = tof(cpowi(0.4, 16));
// halo Kogge-Stone (lane spacing 4)
constexpr float H0_1 = tof(cpowi(0.9, 4)),   H0_2 = tof(cpowi(0.9, 8));
constexpr float H0_4 = tof(cpowi(0.9, 16)),  H0_8 = tof(cpowi(0.9, 32));
constexpr float H0_16 = tof(cpowi(0.9, 64)), H0_32 = tof(cpowi(0.9, 128));
constexpr float H1_1 = tof(cpowi(0.7, 4)),   H1_2 = tof(cpowi(0.7, 8));
constexpr float H1_4 = tof(cpowi(0.7, 16)),  H1_8 = tof(cpowi(0.7, 32));
constexpr float H1_16 = tof(cpowi(0.7, 64));
constexpr float H2_1 = tof(cpowi(0.4, 4)),   H2_2 = tof(cpowi(0.4, 8));
constexpr float H2_4 = tof(cpowi(0.4, 16));

// log2(1-alpha): chunk carry fold weights (1-a)^(16*lane) = exp2(16*lane*log2(1-a))
#define L2_0 (-0.15200309344504997f)
#define L2_1 (-0.51457317282975830f)
#define L2_2 (-1.32192809488736230f)

__device__ __forceinline__ float scan6(float v, int lane, float d1, float d2, float d4,
                                       float d8, float d16, float d32) {
    float u;
    u = __shfl_up(v, 1);  v += (lane >= 1  ? d1  : 0.0f) * u;
    u = __shfl_up(v, 2);  v += (lane >= 2  ? d2  : 0.0f) * u;
    u = __shfl_up(v, 4);  v += (lane >= 4  ? d4  : 0.0f) * u;
    u = __shfl_up(v, 8);  v += (lane >= 8  ? d8  : 0.0f) * u;
    u = __shfl_up(v, 16); v += (lane >= 16 ? d16 : 0.0f) * u;
    u = __shfl_up(v, 32); v += (lane >= 32 ? d32 : 0.0f) * u;
    return v;
}
__device__ __forceinline__ float scan5(float v, int lane, float d1, float d2, float d4,
                                       float d8, float d16) {
    float u;
    u = __shfl_up(v, 1);  v += (lane >= 1  ? d1  : 0.0f) * u;
    u = __shfl_up(v, 2);  v += (lane >= 2  ? d2  : 0.0f) * u;
    u = __shfl_up(v, 4);  v += (lane >= 4  ? d4  : 0.0f) * u;
    u = __shfl_up(v, 8);  v += (lane >= 8  ? d8  : 0.0f) * u;
    u = __shfl_up(v, 16); v += (lane >= 16 ? d16 : 0.0f) * u;
    return v;
}
__device__ __forceinline__ float scan4(float v, int lane, float d1, float d2, float d4, float d8) {
    float u;
    u = __shfl_up(v, 1); v += (lane >= 1 ? d1 : 0.0f) * u;
    u = __shfl_up(v, 2); v += (lane >= 2 ? d2 : 0.0f) * u;
    u = __shfl_up(v, 4); v += (lane >= 4 ? d4 : 0.0f) * u;
    u = __shfl_up(v, 8); v += (lane >= 8 ? d8 : 0.0f) * u;
    return v;
}
__device__ __forceinline__ float scan3(float v, int lane, float d1, float d2, float d4) {
    float u;
    u = __shfl_up(v, 1); v += (lane >= 1 ? d1 : 0.0f) * u;
    u = __shfl_up(v, 2); v += (lane >= 2 ? d2 : 0.0f) * u;
    u = __shfl_up(v, 4); v += (lane >= 4 ? d4 : 0.0f) * u;
    return v;
}
__device__ __forceinline__ float scan2(float v, int lane, float d1, float d2) {
    float u;
    u = __shfl_up(v, 1); v += (lane >= 1 ? d1 : 0.0f) * u;
    u = __shfl_up(v, 2); v += (lane >= 2 ? d2 : 0.0f) * u;
    return v;
}
__device__ __forceinline__ float scan1(float v, int lane, float d1) {
    float u;
    u = __shfl_up(v, 1); v += (lane >= 1 ? d1 : 0.0f) * u;
    return v;
}

__global__ void __launch_bounds__(TPB) msl_main(const float* __restrict__ pred,
                                                const float* __restrict__ targ,
                                                float* __restrict__ partial) {
    const int lane = threadIdx.x & 63;
    const int wave = threadIdx.x >> 6;
    const float* __restrict__ prow = pred + (size_t)blockIdx.x * S_LEN;
    const float* __restrict__ trow = targ + (size_t)blockIdx.x * S_LEN;
    const bool lz = (lane == 0);
    const bool w0 = (wave == 0);

    // carry-fold weights, hoisted (lane-only dependence)
    const float e  = (float)(PER_LANE * lane);
    const float G0 = exp2f(e * L2_0);
    const float G1 = exp2f(e * L2_1);
    const float G2 = exp2f(e * L2_2);

    // ---- halo (first chunk of this wave only; wave 0 starts the row exactly).
    // Recomputes the delta-EMA carry from the preceding 256 elements; truncation
    // weight (1-a)^256 <= 2e-12 (validated r7, absmax 0.0). ----
    float Cp0 = 0.f, Cp1 = 0.f, Cp2 = 0.f, Ct0 = 0.f, Ct1 = 0.f, Ct2 = 0.f;
    float lastp = 0.f, lastt = 0.f;      // element preceding the wave's first chunk
    if (wave > 0) {                       // wave-uniform branch
        const int co0 = wave * CPW * CHUNK;
        float hp[4], ht[4];
        {
            float4 a = *reinterpret_cast<const float4*>(prow + co0 - HALO + lane * 4);
            float4 b = *reinterpret_cast<const float4*>(trow + co0 - HALO + lane * 4);
            hp[0] = a.x; hp[1] = a.y; hp[2] = a.z; hp[3] = a.w;
            ht[0] = b.x; ht[1] = b.y; ht[2] = b.z; ht[3] = b.w;
        }
        float php = __shfl_up(hp[3], 1);
        float pht = __shfl_up(ht[3], 1);
        if (lz) { php = hp[0]; pht = ht[0]; }   // oldest halo dx := 0 (weight ~0)

        float Ap0 = 0.f, Ap1 = 0.f, Ap2 = 0.f, At0 = 0.f, At1 = 0.f, At2 = 0.f;
#pragma unroll
        for (int s = 0; s < 4; ++s) {
            float dxp = hp[s] - php; php = hp[s];
            float dxt = ht[s] - pht; pht = ht[s];
            Ap0 = fmaf(W0f, Ap0, dxp);
            Ap1 = fmaf(W1f, Ap1, dxp);
            Ap2 = fmaf(W2f, Ap2, dxp);
            At0 = fmaf(W0f, At0, dxt);
            At1 = fmaf(W1f, At1, dxt);
            At2 = fmaf(W2f, At2, dxt);
        }
        float vh;
        vh = scan6(Ap0, lane, H0_1, H0_2, H0_4, H0_8, H0_16, H0_32); Cp0 = __shfl(vh, 63);
        vh = scan5(Ap1, lane, H1_1, H1_2, H1_4, H1_8, H1_16);        Cp1 = __shfl(vh, 63);
        vh = scan3(Ap2, lane, H2_1, H2_2, H2_4);                     Cp2 = __shfl(vh, 63);
        vh = scan6(At0, lane, H0_1, H0_2, H0_4, H0_8, H0_16, H0_32); Ct0 = __shfl(vh, 63);
        vh = scan5(At1, lane, H1_1, H1_2, H1_4, H1_8, H1_16);        Ct1 = __shfl(vh, 63);
        vh = scan3(At2, lane, H2_1, H2_2, H2_4);                     Ct2 = __shfl(vh, 63);
        lastp = __shfl(hp[3], 63);
        lastt = __shfl(ht[3], 63);
    }

    float acc0 = 0.f, acc1 = 0.f, acc2 = 0.f;

    // ---- two adjacent chunks; chunk 1's carry is EXACT (lane-63 pass-2 exit).
    // No barriers, no LDS: x stays register-resident (r0 precedent), dx is
    // recomputed in pass 2 (2 subs/elem -- off the contended ds pipe). ----
#pragma unroll
    for (int c = 0; c < CPW; ++c) {
        const int base = (wave * CPW + c) * CHUNK + lane * PER_LANE;
        float xp[PER_LANE], xt[PER_LANE];
        {
            const float4* p4 = reinterpret_cast<const float4*>(prow + base);
            const float4* t4 = reinterpret_cast<const float4*>(trow + base);
#pragma unroll
            for (int j = 0; j < PER_LANE / 4; ++j) {
                float4 a = p4[j];
                float4 b = t4[j];
                xp[4 * j + 0] = a.x; xp[4 * j + 1] = a.y; xp[4 * j + 2] = a.z; xp[4 * j + 3] = a.w;
                xt[4 * j + 0] = b.x; xt[4 * j + 1] = b.y; xt[4 * j + 2] = b.z; xt[4 * j + 3] = b.w;
            }
        }

        // previous element for each lane's first dx
        float pvp = __shfl_up(xp[PER_LANE - 1], 1);
        float pvt = __shfl_up(xt[PER_LANE - 1], 1);
        if (lz) {
            pvp = (w0 && c == 0) ? xp[0] : lastp;   // head: dx_0 = 0
            pvt = (w0 && c == 0) ? xt[0] : lastt;
        }

        // ---- pass 1: lane-local du-EMA on dx, zero carry ----
        float Mp0 = 0.f, Mp1 = 0.f, Mp2 = 0.f, Mt0 = 0.f, Mt1 = 0.f, Mt2 = 0.f;
        float pp = pvp, pt = pvt;
#pragma unroll
        for (int j = 0; j < PER_LANE; ++j) {
            float dxp = xp[j] - pp; pp = xp[j];
            float dxt = xt[j] - pt; pt = xt[j];
            Mp0 = fmaf(W0f, Mp0, dxp);
            Mp1 = fmaf(W1f, Mp1, dxp);
            Mp2 = fmaf(W2f, Mp2, dxp);
            Mt0 = fmaf(W0f, Mt0, dxt);
            Mt1 = fmaf(W1f, Mt1, dxt);
            Mt2 = fmaf(W2f, Mt2, dxt);
        }

        // ---- main scans (spacing 16, pruned) ----
        float vp0 = scan4(Mp0, lane, D0_1, D0_2, D0_4, D0_8);
        float vp1 = scan2(Mp1, lane, D1_1, D1_2);
        float vp2 = scan1(Mp2, lane, D2_1);
        float vt0 = scan4(Mt0, lane, D0_1, D0_2, D0_4, D0_8);
        float vt1 = scan2(Mt1, lane, D1_1, D1_2);
        float vt2 = scan1(Mt2, lane, D2_1);

        // exclusive + carry fold: y_l = (l==0) ? C : v_{l-1} + (1-a)^(16l)*C
        float up0 = __shfl_up(vp0, 1), up1 = __shfl_up(vp1, 1), up2 = __shfl_up(vp2, 1);
        float ut0 = __shfl_up(vt0, 1), ut1 = __shfl_up(vt1, 1), ut2 = __shfl_up(vt2, 1);

        float yp0 = lz ? Cp0 : fmaf(G0, Cp0, up0);
        float yp1 = lz ? Cp1 : fmaf(G1, Cp1, up1);
        float yp2 = lz ? Cp2 : fmaf(G2, Cp2, up2);
        float yt0 = lz ? Ct0 : fmaf(G0, Ct0, ut0);
        float yt1 = lz ? Ct1 : fmaf(G1, Ct1, ut1);
        float yt2 = lz ? Ct2 : fmaf(G2, Ct2, ut2);

        // ---- pass 2: recompute dx, du = fma(W, du, dx), huber on scaled deltas.
        // pd = a*dup, td = a*dut: dir<0 <=> dup*dut<0 ; se = a|dup-dut| ;
        // quad = 0.5*max(1 - a^2*dup*dut, 0)^2. Accumulate 2*h. ----
        const float skip = (w0 && c == 0 && lz) ? 0.0f : 1.0f;
        pp = pvp; pt = pvt;
#pragma unroll
        for (int j = 0; j < PER_LANE; ++j) {
            float dxp = xp[j] - pp; pp = xp[j];
            float dxt = xt[j] - pt; pt = xt[j];
            yp0 = fmaf(W0f, yp0, dxp);
            yt0 = fmaf(W0f, yt0, dxt);
            yp1 = fmaf(W1f, yp1, dxp);
            yt1 = fmaf(W1f, yt1, dxt);
            yp2 = fmaf(W2f, yp2, dxp);
            yt2 = fmaf(W2f, yt2, dxt);

            float m0 = yp0 * yt0, m1 = yp1 * yt1, m2 = yp2 * yt2;
            float se0 = SE0 * fabsf(yp0 - yt0);
            float se1 = SE1 * fabsf(yp1 - yt1);
            float se2 = SE2 * fabsf(yp2 - yt2);
            float mm0 = fmaxf(fmaf(NA0, m0, 1.0f), 0.0f);
            float mm1 = fmaxf(fmaf(NA1, m1, 1.0f), 0.0f);
            float mm2 = fmaxf(fmaf(NA2, m2, 1.0f), 0.0f);
            float h0 = (m0 < 0.0f) ? se0 : mm0 * mm0;
            float h1 = (m1 < 0.0f) ? se1 : mm1 * mm1;
            float h2 = (m2 < 0.0f) ? se2 : mm2 * mm2;
            if (j == 0) { h0 *= skip; h1 *= skip; h2 *= skip; }
            acc0 += h0; acc1 += h1; acc2 += h2;
        }

        // exact carry into the adjacent next chunk (lane-63 exit state)
        if (c + 1 < CPW) {
            Cp0 = __shfl(yp0, 63); Cp1 = __shfl(yp1, 63); Cp2 = __shfl(yp2, 63);
            Ct0 = __shfl(yt0, 63); Ct1 = __shfl(yt1, 63); Ct2 = __shfl(yt2, 63);
            lastp = __shfl(xp[PER_LANE - 1], 63);
            lastt = __shfl(xt[PER_LANE - 1], 63);
        }
    }

    // accumulated 2*h -> weights 0.5*{0.5,0.3,0.2}; wave reduce; per-wave partial
    float wacc = 0.25f * acc0 + 0.15f * acc1 + 0.10f * acc2;
#pragma unroll
    for (int o = 32; o > 0; o >>= 1) wacc += __shfl_down(wacc, o);
    if (lz) partial[blockIdx.x * WPB + wave] = wacc;
}

__global__ void __launch_bounds__(256) msl_reduce(const float* __restrict__ partial,
                                                  float* __restrict__ out) {
    const int tid = threadIdx.x;
    float v = 0.f;
#pragma unroll
    for (int k = 0; k < NPART / 256; ++k) v += partial[tid + 256 * k];
#pragma unroll
    for (int o = 32; o > 0; o >>= 1) v += __shfl_down(v, o);
    __shared__ float s[4];
    if ((tid & 63) == 0) s[tid >> 6] = v;
    __syncthreads();
    if (tid == 0)
        out[0] = (s[0] + s[1] + s[2] + s[3]) *
                 (float)(1.0 / ((double)(S_LEN - 1) * (double)B_ROWS));
}

extern "C" void kernel_launch(void* const* d_in, const int* in_sizes, int n_in,
                              void* d_out, int out_size, void* d_ws, size_t ws_size,
                              hipStream_t stream) {
    const float* pred = (const float*)d_in[0];
    const float* targ = (const float*)d_in[1];
    float* out = (float*)d_out;
    float* partial = (float*)d_ws;  // 8192 floats = 32 KB

    msl_main<<<NBLOCKS, TPB, 0, stream>>>(pred, targ, partial);
    msl_reduce<<<1, 256, 0, stream>>>(partial, out);
}